// Round 1
// baseline (217.183 us; speedup 1.0000x reference)
//
#include <hip/hip_runtime.h>
#include <hip/hip_bf16.h>
#include <stdint.h>

// StrideGraphSAGE on MI355X (gfx950).
// h_l = elu(agg @ Wl[l] + bl[l] + nodes @ Wr[l]); out = concat(h_0..h_3, x) along C.
// agg is nonzero only for rows < 1089 (un-offset edge_index bug in the reference).

#define C_DIM 256
#define N_NODES 1089
#define BATCH 64
#define TOTAL (BATCH * N_NODES)     // 69696
#define M_PAD 69760                 // 545 * 128
#define CN (C_DIM * N_NODES)        // 278784
#define OUT_STRIDE_B (5 * CN)       // 1393920
#define NCOLS 1024                  // 4 layers * 256
#define AGG_ROWS 1152               // 9*128, zero-padded past 1089

using bf16 = __hip_bfloat16;
typedef __attribute__((ext_vector_type(8))) short short8;
typedef __attribute__((ext_vector_type(4))) float f32x4;

// ---- workspace layout (bytes) ----
#define NODES_BYTES ((size_t)M_PAD * C_DIM * 2)      // 35,717,120
#define OFF_NODES   ((size_t)0)
#define OFF_AGGF    (NODES_BYTES)
#define AGGF_BYTES  ((size_t)AGG_ROWS * C_DIM * 4)   // 1,179,648
#define OFF_DEG     (OFF_AGGF + AGGF_BYTES)
#define DEG_BYTES   ((size_t)AGG_ROWS * 4)           // 4,608
#define OFF_AGGB    (OFF_DEG + DEG_BYTES)
#define AGGB_BYTES  ((size_t)AGG_ROWS * C_DIM * 2)   // 589,824
#define OFF_WLT     (OFF_AGGB + AGGB_BYTES)
#define WT_BYTES    ((size_t)NCOLS * C_DIM * 2)      // 524,288
#define OFF_WRT     (OFF_WLT + WT_BYTES)

__device__ __forceinline__ void gload16(void* lds, const void* g) {
    __builtin_amdgcn_global_load_lds(
        (const __attribute__((address_space(1))) uint32_t*)g,
        (__attribute__((address_space(3))) uint32_t*)lds,
        16, 0, 0);
}

// ---- x [B,C,N] f32 -> nodes [B*N, C] bf16 ; also copy x into out block 4 ----
__global__ __launch_bounds__(256)
void transpose_kernel(const float* __restrict__ x, bf16* __restrict__ nodes,
                      float* __restrict__ out)
{
    __shared__ bf16 tile[256][66];   // [c][n], row stride 132B -> phase2 bank stride 33 (cf)
    const int t = threadIdx.x;
    const int bid = blockIdx.x;
    const int b = bid / 18;
    const int n0 = (bid % 18) * 64;
    const int nl = t & 63;
    const int cs = t >> 6;           // 0..3
    const int n = n0 + nl;
    const bool nvalid = n < N_NODES;
    const float* xb = x + (size_t)b * CN;
    float* outb = out + (size_t)b * OUT_STRIDE_B + (size_t)4 * CN;
#pragma unroll 4
    for (int cc = 0; cc < 64; ++cc) {
        int c = cc * 4 + cs;
        if (nvalid) {
            float v = xb[(size_t)c * N_NODES + n];
            outb[(size_t)c * N_NODES + n] = v;           // concat block 4 = x
            tile[c][nl] = __float2bfloat16(v);
        }
    }
    __syncthreads();
    const int half = t >> 7;             // 0..1
    const int c0 = (t & 127) * 2;
#pragma unroll
    for (int it = 0; it < 32; ++it) {
        int row = it * 2 + half;
        int nr = n0 + row;
        if (nr < N_NODES) {
            __hip_bfloat162 p;
            p.x = tile[c0][row];
            p.y = tile[c0 + 1][row];
            *(__hip_bfloat162*)(nodes + ((size_t)b * N_NODES + nr) * C_DIM + c0) = p;
        }
    }
}

// ---- W[l][k][c] f32 -> WT[l*256+c][k] bf16 (B^T layout so GEMM B-frags are b128) ----
__global__ __launch_bounds__(256)
void wtrans_kernel(const float* __restrict__ Wl, const float* __restrict__ Wr,
                   bf16* __restrict__ WlT, bf16* __restrict__ WrT)
{
    __shared__ float tile[64][65];
    const int bid = blockIdx.x;          // 7 bits: sel(1) l(2) kt(2) ct(2)
    const int sel = bid & 1;
    const int l = (bid >> 1) & 3;
    const int kt = ((bid >> 3) & 3) * 64;
    const int ct = ((bid >> 5) & 3) * 64;
    const float* W = sel ? Wr : Wl;
    bf16* WT = sel ? WrT : WlT;
    const int tc = threadIdx.x & 63;
    const int tk = threadIdx.x >> 6;
#pragma unroll
    for (int i = 0; i < 16; ++i) {
        int kl = i * 4 + tk;
        tile[kl][tc] = W[((size_t)(l * 256 + kt + kl)) * 256 + ct + tc];
    }
    __syncthreads();
#pragma unroll
    for (int i = 0; i < 16; ++i) {
        int cl = i * 4 + tk;
        WT[((size_t)(l * 256 + ct + cl)) * 256 + kt + tc] = __float2bfloat16(tile[tc][cl]);
    }
}

__global__ void deg_kernel(const int* __restrict__ dst, int E, float* __restrict__ deg) {
    int e = blockIdx.x * 256 + threadIdx.x;
    if (e < E) atomicAdd(&deg[dst[e]], 1.0f);
}

__global__ __launch_bounds__(256)
void scatter_kernel(const int* __restrict__ src, const int* __restrict__ dst,
                    const bf16* __restrict__ nodes, float* __restrict__ aggf)
{
    const int e = blockIdx.x;
    const int s = src[e], d = dst[e];
    const int c = threadIdx.x;
    atomicAdd(&aggf[(size_t)d * C_DIM + c],
              __bfloat162float(nodes[(size_t)s * C_DIM + c]));
}

__global__ __launch_bounds__(256)
void finalize_kernel(const float* __restrict__ aggf, const float* __restrict__ deg,
                     bf16* __restrict__ aggb)
{
    const int n = blockIdx.x;
    const int c = threadIdx.x;
    float dg = deg[n];
    float inv = dg > 0.f ? 1.f / dg : 0.f;
    aggb[(size_t)n * C_DIM + c] = __float2bfloat16(aggf[(size_t)n * C_DIM + c] * inv);
}

// ---- fused GEMM: out = elu(nodes@WrT^T + [agg@WlT^T] + bias), scrambled store ----
// 128x128 tile, 4 waves (2x2 of 64x64), 16x16x32 bf16 MFMA, global_load_lds width 16.
__global__ __launch_bounds__(256)
void gemm_kernel(const bf16* __restrict__ nodes, const bf16* __restrict__ agg,
                 const bf16* __restrict__ WrT, const bf16* __restrict__ WlT,
                 const float* __restrict__ bias, float* __restrict__ out)
{
    __shared__ bf16 Alds[128 * 32];
    __shared__ bf16 Blds[128 * 32];
    const int t = threadIdx.x;
    const int lane = t & 63;
    const int w = t >> 6;
    const int brow = blockIdx.y;
    const int bcol = blockIdx.x;

    f32x4 acc[4][4] = {};

    const int tq = t >> 2;           // staging row (issue 0); issue 1 adds 64
    const int kk = (t & 3) << 3;     // staging k-offset (bf16 elems)
    const int wr = (w >> 1) << 6;    // wave row offset in tile
    const int wc = (w & 1) << 6;     // wave col offset in tile
    const int fr = lane & 15;
    const int kq = lane >> 4;

    char* AldsB = (char*)Alds;
    char* BldsB = (char*)Blds;
    const short* AldsS = (const short*)Alds;
    const short* BldsS = (const short*)Blds;

    const int npass = (brow * 128 < N_NODES) ? 2 : 1;
    for (int pass = 0; pass < npass; ++pass) {
        const bf16* Ag = (pass == 0 ? nodes : agg) + (size_t)brow * 128 * C_DIM;
        const bf16* Bg = (pass == 0 ? WrT : WlT) + (size_t)bcol * 128 * C_DIM;
        for (int k0 = 0; k0 < C_DIM; k0 += 32) {
            // stage A and B^T tiles: [128][32] bf16 each, 2 x 4KB issues apiece
            gload16(AldsB + w * 1024,        Ag + (size_t)tq * C_DIM + k0 + kk);
            gload16(AldsB + 4096 + w * 1024, Ag + (size_t)(64 + tq) * C_DIM + k0 + kk);
            gload16(BldsB + w * 1024,        Bg + (size_t)tq * C_DIM + k0 + kk);
            gload16(BldsB + 4096 + w * 1024, Bg + (size_t)(64 + tq) * C_DIM + k0 + kk);
            __syncthreads();   // compiler drains vmcnt before s_barrier
            short8 av[4], bv[4];
#pragma unroll
            for (int m = 0; m < 4; ++m)
                av[m] = *(const short8*)(AldsS + (wr + m * 16 + fr) * 32 + kq * 8);
#pragma unroll
            for (int n = 0; n < 4; ++n)
                bv[n] = *(const short8*)(BldsS + (wc + n * 16 + fr) * 32 + kq * 8);
#pragma unroll
            for (int m = 0; m < 4; ++m)
#pragma unroll
                for (int n = 0; n < 4; ++n)
                    acc[m][n] = __builtin_amdgcn_mfma_f32_16x16x32_bf16(
                        av[m], bv[n], acc[m][n], 0, 0, 0);
            __syncthreads();   // all reads done before next stage overwrites
        }
    }

    // epilogue: bias + ELU + scrambled store
    const int rq = (lane >> 4) * 4;
#pragma unroll
    for (int m = 0; m < 4; ++m) {
#pragma unroll
        for (int reg = 0; reg < 4; ++reg) {
            int r = brow * 128 + wr + m * 16 + rq + reg;
            if (r < TOTAL) {
                unsigned bb = (unsigned)r / N_NODES;
                int nn = r - (int)bb * N_NODES;
                size_t base = (size_t)bb * OUT_STRIDE_B + (size_t)nn * C_DIM;
#pragma unroll
                for (int n = 0; n < 4; ++n) {
                    int col = bcol * 128 + wc + n * 16 + fr;
                    float v = acc[m][n][reg] + bias[col];
                    v = v > 0.f ? v : expm1f(v);
                    int l = col >> 8, c = col & 255;
                    out[base + (size_t)l * CN + c] = v;
                }
            }
        }
    }
}

extern "C" void kernel_launch(void* const* d_in, const int* in_sizes, int n_in,
                              void* d_out, int out_size, void* d_ws, size_t ws_size,
                              hipStream_t stream) {
    const float* x  = (const float*)d_in[0];
    const float* Wl = (const float*)d_in[1];
    const float* bl = (const float*)d_in[2];
    const float* Wr = (const float*)d_in[3];
    const int* src  = (const int*)d_in[4];
    const int* dst  = (const int*)d_in[5];
    const int E = in_sizes[4];
    float* out = (float*)d_out;
    char* ws = (char*)d_ws;

    bf16*  nodes = (bf16*)(ws + OFF_NODES);
    float* aggf  = (float*)(ws + OFF_AGGF);
    float* deg   = (float*)(ws + OFF_DEG);
    bf16*  aggb  = (bf16*)(ws + OFF_AGGB);
    bf16*  WlT   = (bf16*)(ws + OFF_WLT);
    bf16*  WrT   = (bf16*)(ws + OFF_WRT);

    // zero agg accumulators + deg + padded agg bf16 (contiguous region), every call
    hipMemsetAsync(ws + OFF_AGGF, 0, AGGF_BYTES + DEG_BYTES + AGGB_BYTES, stream);

    wtrans_kernel<<<128, 256, 0, stream>>>(Wl, Wr, WlT, WrT);
    transpose_kernel<<<BATCH * 18, 256, 0, stream>>>(x, nodes, out);
    deg_kernel<<<(E + 255) / 256, 256, 0, stream>>>(dst, E, deg);
    scatter_kernel<<<E, 256, 0, stream>>>(src, dst, nodes, aggf);
    finalize_kernel<<<N_NODES, 256, 0, stream>>>(aggf, deg, aggb);
    gemm_kernel<<<dim3(8, 545), 256, 0, stream>>>(nodes, aggb, WrT, WlT, bl, out);
}

// Round 2
// 179.182 us; speedup vs baseline: 1.2121x; 1.2121x over previous
//
#include <hip/hip_runtime.h>
#include <hip/hip_bf16.h>
#include <stdint.h>

// StrideGraphSAGE on MI355X (gfx950).
// h_l = elu(agg @ Wl[l] + bl[l] + nodes @ Wr[l]); out = concat(h_0..h_3, x) along C.
// agg is nonzero only for rows < 1089 (un-offset edge_index bug in the reference).

#define C_DIM 256
#define N_NODES 1089
#define BATCH 64
#define TOTAL (BATCH * N_NODES)     // 69696
#define M_PAD 69760                 // 545 * 128
#define CN (C_DIM * N_NODES)        // 278784
#define OUT_STRIDE_B (5 * CN)       // 1393920
#define NCOLS 1024                  // 4 layers * 256
#define AGG_ROWS 1152               // 9*128, zero-padded past 1089

using bf16 = __hip_bfloat16;
typedef __attribute__((ext_vector_type(8))) short short8;
typedef __attribute__((ext_vector_type(4))) float f32x4;
typedef __attribute__((ext_vector_type(4))) unsigned int uint4v;

// ---- workspace layout (bytes) ----
#define NODES_BYTES ((size_t)M_PAD * C_DIM * 2)      // 35,717,120
#define OFF_NODES   ((size_t)0)
#define OFF_AGGF    (NODES_BYTES)
#define AGGF_BYTES  ((size_t)AGG_ROWS * C_DIM * 4)   // 1,179,648
#define OFF_DEG     (OFF_AGGF + AGGF_BYTES)
#define DEG_BYTES   ((size_t)AGG_ROWS * 4)           // 4,608
#define OFF_AGGB    (OFF_DEG + DEG_BYTES)
#define AGGB_BYTES  ((size_t)AGG_ROWS * C_DIM * 2)   // 589,824
#define OFF_WLT     (OFF_AGGB + AGGB_BYTES)
#define WT_BYTES    ((size_t)NCOLS * C_DIM * 2)      // 524,288
#define OFF_WRT     (OFF_WLT + WT_BYTES)
#define ZERO_BYTES  (AGGF_BYTES + DEG_BYTES + AGGB_BYTES)  // 1,774,080
#define ZERO_N16    (ZERO_BYTES / 16)                       // 110,880

__device__ __forceinline__ void gload16(void* lds, const void* g) {
    __builtin_amdgcn_global_load_lds(
        (const __attribute__((address_space(1))) uint32_t*)g,
        (__attribute__((address_space(3))) uint32_t*)lds,
        16, 0, 0);
}

__global__ __launch_bounds__(256)
void zero_kernel(uint4v* __restrict__ p) {
    int i = blockIdx.x * 256 + threadIdx.x;
    if (i < ZERO_N16) p[i] = (uint4v){0, 0, 0, 0};
}

// ---- x [B,C,N] f32 -> nodes [B*N, C] bf16 ; also copy x into out block 4 ----
__global__ __launch_bounds__(256)
void transpose_kernel(const float* __restrict__ x, bf16* __restrict__ nodes,
                      float* __restrict__ out)
{
    __shared__ bf16 tile[256][66];   // [c][n], row stride 132B
    const int t = threadIdx.x;
    const int bid = blockIdx.x;
    const int b = bid / 18;
    const int n0 = (bid % 18) * 64;
    const int nl = t & 63;
    const int cs = t >> 6;           // 0..3
    const int n = n0 + nl;
    const bool nvalid = n < N_NODES;
    const float* xb = x + (size_t)b * CN;
    float* outb = out + (size_t)b * OUT_STRIDE_B + (size_t)4 * CN;
#pragma unroll 4
    for (int cc = 0; cc < 64; ++cc) {
        int c = cc * 4 + cs;
        if (nvalid) {
            float v = xb[(size_t)c * N_NODES + n];
            outb[(size_t)c * N_NODES + n] = v;           // concat block 4 = x
            tile[c][nl] = __float2bfloat16(v);
        }
    }
    __syncthreads();
    const int half = t >> 7;             // 0..1
    const int c0 = (t & 127) * 2;
#pragma unroll
    for (int it = 0; it < 32; ++it) {
        int row = it * 2 + half;
        int nr = n0 + row;
        if (nr < N_NODES) {
            __hip_bfloat162 p;
            p.x = tile[c0][row];
            p.y = tile[c0 + 1][row];
            *(__hip_bfloat162*)(nodes + ((size_t)b * N_NODES + nr) * C_DIM + c0) = p;
        }
    }
}

// ---- W[l][k][c] f32 -> WT[l*256+c][k] bf16 (B^T layout) ----
__global__ __launch_bounds__(256)
void wtrans_kernel(const float* __restrict__ Wl, const float* __restrict__ Wr,
                   bf16* __restrict__ WlT, bf16* __restrict__ WrT)
{
    __shared__ float tile[64][65];
    const int bid = blockIdx.x;          // 7 bits: sel(1) l(2) kt(2) ct(2)
    const int sel = bid & 1;
    const int l = (bid >> 1) & 3;
    const int kt = ((bid >> 3) & 3) * 64;
    const int ct = ((bid >> 5) & 3) * 64;
    const float* W = sel ? Wr : Wl;
    bf16* WT = sel ? WrT : WlT;
    const int tc = threadIdx.x & 63;
    const int tk = threadIdx.x >> 6;
#pragma unroll
    for (int i = 0; i < 16; ++i) {
        int kl = i * 4 + tk;
        tile[kl][tc] = W[((size_t)(l * 256 + kt + kl)) * 256 + ct + tc];
    }
    __syncthreads();
#pragma unroll
    for (int i = 0; i < 16; ++i) {
        int cl = i * 4 + tk;
        WT[((size_t)(l * 256 + ct + cl)) * 256 + kt + tc] = __float2bfloat16(tile[tc][cl]);
    }
}

__global__ void deg_kernel(const int* __restrict__ dst, int E, float* __restrict__ deg) {
    int e = blockIdx.x * 256 + threadIdx.x;
    if (e < E) atomicAdd(&deg[dst[e]], 1.0f);
}

__global__ __launch_bounds__(256)
void scatter_kernel(const int* __restrict__ src, const int* __restrict__ dst,
                    const bf16* __restrict__ nodes, float* __restrict__ aggf)
{
    const int e = blockIdx.x;
    const int s = src[e], d = dst[e];
    const int c = threadIdx.x;
    atomicAdd(&aggf[(size_t)d * C_DIM + c],
              __bfloat162float(nodes[(size_t)s * C_DIM + c]));
}

__global__ __launch_bounds__(256)
void finalize_kernel(const float* __restrict__ aggf, const float* __restrict__ deg,
                     bf16* __restrict__ aggb)
{
    const int n = blockIdx.x;
    const int c = threadIdx.x;
    float dg = deg[n];
    float inv = dg > 0.f ? 1.f / dg : 0.f;
    aggb[(size_t)n * C_DIM + c] = __float2bfloat16(aggf[(size_t)n * C_DIM + c] * inv);
}

// ---- fused GEMM: out = elu(nodes@WrT^T + [agg@WlT^T] + bias), scrambled store ----
// 128x128 tile, 4 waves, 16x16x32 bf16 MFMA, 2-phase double-buffered staging,
// XOR-swizzled LDS (both-sides: pre-swizzled gload source + swizzled ds_read).
__global__ __launch_bounds__(256)
void gemm_kernel(const bf16* __restrict__ nodes, const bf16* __restrict__ agg,
                 const bf16* __restrict__ WrT, const bf16* __restrict__ WlT,
                 const float* __restrict__ bias, float* __restrict__ out)
{
    __shared__ bf16 Alds[2][128 * 32];
    __shared__ bf16 Blds[2][128 * 32];
    const int t = threadIdx.x;
    const int lane = t & 63;
    const int w = t >> 6;
    const int brow = blockIdx.y;
    const int bcol = blockIdx.x;

    f32x4 acc[4][4] = {};

    // staging: lane covers row tq, 16B slot (t&3); swizzle: phys slot s holds
    // logical slot s ^ ((row>>1)&3)  -> fetch that logical slot from global.
    const int tq = t >> 2;                               // rows 0..63 (+64 for issue 1)
    const int kk = (((t & 3) ^ ((tq >> 1) & 3)) << 3);   // same for row tq+64 (64%8==0)
    const int wr = (w >> 1) << 6;
    const int wc = (w & 1) << 6;
    const int fr = lane & 15;
    const int kq = lane >> 4;
    const int swz = (kq ^ ((fr >> 1) & 3)) << 3;         // phys 16B slot for reads (in shorts)

    char* AldsB = (char*)Alds;
    char* BldsB = (char*)Blds;
    const short* AldsS = (const short*)Alds;
    const short* BldsS = (const short*)Blds;

    const int nsteps = (brow * 128 < N_NODES) ? 16 : 8;
    const bf16* Abase0 = nodes + (size_t)brow * 128 * C_DIM;
    const bf16* Abase1 = agg + (size_t)brow * 128 * C_DIM;
    const bf16* Bbase0 = WrT + (size_t)bcol * 128 * C_DIM;
    const bf16* Bbase1 = WlT + (size_t)bcol * 128 * C_DIM;

    auto STAGE = [&](int s, int buf) {
        const int k0 = (s & 7) * 32;
        const bf16* Ag = (s < 8 ? Abase0 : Abase1) + (size_t)tq * C_DIM + k0 + kk;
        const bf16* Bg = (s < 8 ? Bbase0 : Bbase1) + (size_t)tq * C_DIM + k0 + kk;
        gload16(AldsB + buf * 8192 + w * 1024,        Ag);
        gload16(AldsB + buf * 8192 + 4096 + w * 1024, Ag + 64 * C_DIM);
        gload16(BldsB + buf * 8192 + w * 1024,        Bg);
        gload16(BldsB + buf * 8192 + 4096 + w * 1024, Bg + 64 * C_DIM);
    };

    STAGE(0, 0);
    __syncthreads();     // drains vmcnt before barrier
    int cur = 0;
    for (int s = 0; s < nsteps; ++s) {
        if (s + 1 < nsteps) STAGE(s + 1, cur ^ 1);   // prefetch next (in flight across compute)
        short8 av[4], bv[4];
#pragma unroll
        for (int m = 0; m < 4; ++m)
            av[m] = *(const short8*)(AldsS + cur * 4096 + (wr + m * 16 + fr) * 32 + swz);
#pragma unroll
        for (int n = 0; n < 4; ++n)
            bv[n] = *(const short8*)(BldsS + cur * 4096 + (wc + n * 16 + fr) * 32 + swz);
#pragma unroll
        for (int m = 0; m < 4; ++m)
#pragma unroll
            for (int n = 0; n < 4; ++n)
                acc[m][n] = __builtin_amdgcn_mfma_f32_16x16x32_bf16(
                    av[m], bv[n], acc[m][n], 0, 0, 0);
        __syncthreads();  // my ds_reads done; prefetch drained (vmcnt 0) -> safe to swap
        cur ^= 1;
    }

    // epilogue: bias + fast ELU + scrambled store
    const int rq = (lane >> 4) * 4;
    const int r0 = brow * 128 + wr + rq;
    const unsigned bb0 = (unsigned)r0 / N_NODES;         // one divide per lane
    const int rsw = (int)((bb0 + 1) * N_NODES);
    const int colbase = bcol * 128 + wc + fr;
    size_t coff[4];
    float bi[4];
#pragma unroll
    for (int n = 0; n < 4; ++n) {
        int col = colbase + n * 16;
        coff[n] = (size_t)(col >> 8) * CN + (col & 255);
        bi[n] = bias[col];
    }
#pragma unroll
    for (int m = 0; m < 4; ++m) {
#pragma unroll
        for (int reg = 0; reg < 4; ++reg) {
            int r = r0 + m * 16 + reg;
            if (r < TOTAL) {
                int bb = (int)bb0 + (r >= rsw ? 1 : 0);
                int nn = r - bb * N_NODES;
                size_t base = (size_t)bb * OUT_STRIDE_B + (size_t)nn * C_DIM;
#pragma unroll
                for (int n = 0; n < 4; ++n) {
                    float v = acc[m][n][reg] + bi[n];
                    v = v > 0.f ? v : (__expf(v) - 1.0f);
                    out[base + coff[n]] = v;
                }
            }
        }
    }
}

extern "C" void kernel_launch(void* const* d_in, const int* in_sizes, int n_in,
                              void* d_out, int out_size, void* d_ws, size_t ws_size,
                              hipStream_t stream) {
    const float* x  = (const float*)d_in[0];
    const float* Wl = (const float*)d_in[1];
    const float* bl = (const float*)d_in[2];
    const float* Wr = (const float*)d_in[3];
    const int* src  = (const int*)d_in[4];
    const int* dst  = (const int*)d_in[5];
    const int E = in_sizes[4];
    float* out = (float*)d_out;
    char* ws = (char*)d_ws;

    bf16*  nodes = (bf16*)(ws + OFF_NODES);
    float* aggf  = (float*)(ws + OFF_AGGF);
    float* deg   = (float*)(ws + OFF_DEG);
    bf16*  aggb  = (bf16*)(ws + OFF_AGGB);
    bf16*  WlT   = (bf16*)(ws + OFF_WLT);
    bf16*  WrT   = (bf16*)(ws + OFF_WRT);

    zero_kernel<<<(ZERO_N16 + 255) / 256, 256, 0, stream>>>((uint4v*)(ws + OFF_AGGF));
    wtrans_kernel<<<128, 256, 0, stream>>>(Wl, Wr, WlT, WrT);
    transpose_kernel<<<BATCH * 18, 256, 0, stream>>>(x, nodes, out);
    deg_kernel<<<(E + 255) / 256, 256, 0, stream>>>(dst, E, deg);
    scatter_kernel<<<E, 256, 0, stream>>>(src, dst, nodes, aggf);
    finalize_kernel<<<N_NODES, 256, 0, stream>>>(aggf, deg, aggb);
    gemm_kernel<<<dim3(8, 545), 256, 0, stream>>>(nodes, aggb, WrT, WlT, bl, out);
}